// Round 28
// baseline (774.070 us; speedup 1.0000x reference)
//
#include <hip/hip_runtime.h>

typedef _Float16 f16;
typedef _Float16 f16x8 __attribute__((ext_vector_type(8)));
typedef float    f32x4 __attribute__((ext_vector_type(4)));
typedef float    f32x16 __attribute__((ext_vector_type(16)));

static __device__ __forceinline__ f16x8 ld8(const f16* p) {
    return *reinterpret_cast<const f16x8*>(p);
}

// ---------------- ws layout (bytes) ----------------
// Activations are CHUNK-BLOCKED: [b][cb][30][30][32] f16 (cb = channel/32).
static constexpr size_t W1T_B  = 1253376;  // 9*17*4*128*8 f16 (32x32 layout)
static constexpr size_t W2T_B  = 147456;   // 9*4*4*64*8  (32x32 layout)
static constexpr size_t W3T_B  = 36864;    // 9*2*4*32*8  (32x32 layout)
static constexpr size_t W4T_B  = 9216;     // 9*1*4*16*8  (16x16 layout)
static constexpr size_t FW1T_B = 6422528;  // 256*12544 f16
static constexpr size_t WEIGHTS_B = W1T_B + W2T_B + W3T_B + W4T_B + FW1T_B; // 7,869,440

static constexpr size_t PB_X0 = 979200;    // 17 chunks * 900 * 32 f16
static constexpr size_t PB_X1 = 230400;    // 4 chunks
static constexpr size_t PB_X2 = 115200;    // 2 chunks
static constexpr size_t PB_X3 = 57600;     // 1 chunk
static constexpr size_t PB_X4 = 25088;     // 28*28*16 flat (fc1 k-order)
static constexpr size_t PB_X5 = 512;       // 256 f16
static constexpr size_t PER_BATCH = PB_X0 + PB_X1 + PB_X2 + PB_X3 + PB_X4 + PB_X5; // 1,408,000

// ---------------- merged weight prep (one dispatch) ----------------
// 16x16 layout (conv4): [tap][cb][hi][co][j8], ci = cb*32 + hi*8 + j
static __device__ __forceinline__ void wxf(const float* __restrict__ w, f16* __restrict__ wt,
                                           int i, int CINr, int NCB, int COUT) {
    int co = i % COUT;
    int r  = i / COUT;
    int hi = r & 3; r >>= 2;
    int cb = r % NCB;
    int tap = r / NCB;
    f16x8 v;
    #pragma unroll
    for (int j = 0; j < 8; ++j) {
        int ci = cb * 32 + hi * 8 + j;
        float x = (ci < CINr) ? w[((size_t)co * CINr + ci) * 9 + tap] : 0.f;
        v[j] = (f16)x;
    }
    *reinterpret_cast<f16x8*>(wt + (size_t)i * 8) = v;
}

// 32x32x16 layout (conv1-3): [tap][cb][kh(2)][g(2)][co][j8],
// ci = cb*32 + kh*16 + g*8 + j  (g = lane>>5 k-subgroup; pairing positional)
static __device__ __forceinline__ void wxf32g(const float* __restrict__ w,
                                              f16* __restrict__ wt, int i,
                                              int CINr, int NCB, int COUT) {
    int co = i % COUT;
    int r  = i / COUT;
    int g  = r & 1; r >>= 1;
    int kh = r & 1; r >>= 1;
    int cb = r % NCB;
    int tap = r / NCB;
    f16x8 v;
    #pragma unroll
    for (int j = 0; j < 8; ++j) {
        int ci = cb * 32 + kh * 16 + g * 8 + j;
        float x = (ci < CINr) ? w[((size_t)co * CINr + ci) * 9 + tap] : 0.f;
        v[j] = (f16)x;
    }
    *reinterpret_cast<f16x8*>(wt + (size_t)i * 8) = v;
}

static constexpr int S1 = 9 * 17 * 4 * 128;   // 78336 vec8 items
static constexpr int S2 = 9 * 4  * 4 * 64;    // 9216
static constexpr int S3 = 9 * 2  * 4 * 32;    // 2304
static constexpr int S4 = 9 * 1  * 4 * 16;    // 576
static constexpr int SW = S1 + S2 + S3 + S4;  // 90432
static constexpr int SFW = 256 * 12544;       // 3211264 scalar f16
static constexpr int PREP_TOT = SW + SFW;

__global__ void prep_all(const float* __restrict__ w1, const float* __restrict__ w2,
                         const float* __restrict__ w3, const float* __restrict__ w4,
                         const float* __restrict__ fw1,
                         f16* __restrict__ W1t, f16* __restrict__ W2t,
                         f16* __restrict__ W3t, f16* __restrict__ W4t,
                         f16* __restrict__ FW1t) {
    int t = blockIdx.x * 256 + threadIdx.x;
    if (t >= PREP_TOT) return;
    if (t < S1) { wxf32g(w1, W1t, t, 516, 17, 128); return; }
    t -= S1;
    if (t < S2) { wxf32g(w2, W2t, t, 128, 4, 64); return; }
    t -= S2;
    if (t < S3) { wxf32g(w3, W3t, t, 64, 2, 32); return; }
    t -= S3;
    if (t < S4) { wxf(w4, W4t, t, 32, 1, 16); return; }
    t -= S4;
    // fw1t[o][y*448 + x*16 + c] = fw1[o][c*784 + y*28 + x]  (k-order matches X4 flat)
    int o = t / 12544, idx = t % 12544;
    int y = idx / 448, rem = idx % 448;
    int x = rem / 16, c = rem & 15;
    FW1t[t] = (f16)fw1[(size_t)o * 12544 + c * 784 + y * 28 + x];
}

// ---------------- fused X0/ring builder (chunk-blocked): one block per batch ----------------
static __device__ __forceinline__ void ring_yx(int bi, int& y, int& x) {
    // 116 border pixels of a 30x30 tile
    if (bi < 30)      { y = 0;        x = bi; }
    else if (bi < 60) { y = 29;       x = bi - 30; }
    else if (bi < 88) { y = bi - 59;  x = 0; }      // 1..28
    else              { y = bi - 87;  x = 29; }     // 1..28
}

__global__ __launch_bounds__(512) void build_x0(
        const float* __restrict__ img, const float* __restrict__ feat,
        const float* __restrict__ centers,
        f16* __restrict__ X0, f16* __restrict__ X1,
        f16* __restrict__ X2, f16* __restrict__ X3, int b0) {
    const int bl = blockIdx.x;            // chunk-local batch
    const int b  = b0 + bl;               // global batch
    const int tid = threadIdx.x;
    f16* x0b = X0 + (size_t)bl * (17 * 900 * 32);

    // (a) X0 border ring, all 544 ch  (chunk cb=c>>5, lane c&31)
    for (int i = tid; i < 116 * 544; i += 512) {
        int c = i % 544, bi = i / 544;
        int y, x; ring_yx(bi, y, x);
        x0b[((size_t)(c >> 5) * 900 + y * 30 + x) * 32 + (c & 31)] = (f16)0.f;
    }
    // (b) cmap plane interior zero (ch 515 -> chunk 16, lane 3)
    for (int i = tid; i < 784; i += 512) {
        int y = i / 28, x = i % 28;
        x0b[((size_t)16 * 900 + (y + 1) * 30 + x + 1) * 32 + 3] = (f16)0.f;
    }
    // (c) image fill (ch 0..2 -> chunk 0)
    for (int i = tid; i < 3 * 784; i += 512) {
        int c = i / 784, p = i % 784;
        int y = p / 28, x = p % 28;
        x0b[((size_t)(y + 1) * 30 + x + 1) * 32 + c] =
            (f16)img[((size_t)b * 3 + c) * 784 + p];
    }
    // (d) bilinear 7x7 -> 28x28; tid = feat channel, maps to ch tid+3
    {
        const int c  = tid + 3;
        const int cb = c >> 5, c32 = c & 31;
        const float* fb = feat + ((size_t)b * 512 + tid) * 49;
        float r0[7], r1[7];
        int cur = -100;
        for (int y = 0; y < 28; ++y) {
            float sy = (y + 0.5f) * 0.25f - 0.5f;
            float fy = floorf(sy);
            int iy0 = (int)fy;
            float wy1 = sy - fy, wy0 = 1.f - wy1;
            if (iy0 != cur) {
                cur = iy0;
                int i0 = iy0 < 0 ? 0 : iy0;
                int i1 = (iy0 + 1 > 6) ? 6 : iy0 + 1;
                #pragma unroll
                for (int j = 0; j < 7; ++j) { r0[j] = fb[i0 * 7 + j]; r1[j] = fb[i1 * 7 + j]; }
            }
            f16* orow = x0b + ((size_t)cb * 900 + (y + 1) * 30 + 1) * 32 + c32;
            #pragma unroll 28
            for (int x = 0; x < 28; ++x) {
                float sx = (x + 0.5f) * 0.25f - 0.5f;
                float fx = floorf(sx);
                int ix0 = (int)fx;
                float wx1 = sx - fx, wx0 = 1.f - wx1;
                int j0 = ix0 < 0 ? 0 : ix0;
                int j1 = (ix0 + 1 > 6) ? 6 : ix0 + 1;
                float v = wy0 * (wx0 * r0[j0] + wx1 * r0[j1]) +
                          wy1 * (wx0 * r1[j0] + wx1 * r1[j1]);
                orow[(size_t)x * 32] = (f16)v;
            }
        }
    }
    // (e) X1/X2/X3 border rings (chunk-blocked)
    {
        f16* x1b = X1 + (size_t)bl * (4 * 900 * 32);
        for (int i = tid; i < 116 * 128; i += 512) {
            int c = i % 128, bi = i / 128;
            int y, x; ring_yx(bi, y, x);
            x1b[((size_t)(c >> 5) * 900 + y * 30 + x) * 32 + (c & 31)] = (f16)0.f;
        }
        f16* x2b = X2 + (size_t)bl * (2 * 900 * 32);
        for (int i = tid; i < 116 * 64; i += 512) {
            int c = i % 64, bi = i / 64;
            int y, x; ring_yx(bi, y, x);
            x2b[((size_t)(c >> 5) * 900 + y * 30 + x) * 32 + (c & 31)] = (f16)0.f;
        }
        f16* x3b = X3 + (size_t)bl * (900 * 32);
        for (int i = tid; i < 116 * 32; i += 512) {
            int c = i % 32, bi = i / 32;
            int y, x; ring_yx(bi, y, x);
            x3b[((size_t)y * 30 + x) * 32 + c] = (f16)0.f;
        }
    }
    __syncthreads();
    // (f) sequential scatter, last-write-wins (matches np order); ch 515 -> chunk16 lane3
    if (tid == 0) {
        const float* cb = centers + (size_t)b * 400;
        for (int n = 0; n < 100; ++n) {
            float cx = cb[n * 4 + 0], cy = cb[n * 4 + 1], conf = cb[n * 4 + 3];
            int xp = (int)(cx * 28.f);
            int yp = (int)(cy * 28.f);
            if (xp >= 0 && xp < 28 && yp >= 0 && yp < 28)
                x0b[((size_t)16 * 900 + (yp + 1) * 30 + xp + 1) * 32 + 3] = (f16)conf;
        }
    }
}

// ---------------- conv1-3: 32x32x16 MFMA template ----------------
// 8-row blocks = 224 px = 7 m-tiles of 32 -> 7 waves (448 thr), each wave
// owns 1 m-tile x NCO co-tiles. NBUF=2 (conv1): double-buffered LDS panels --
// next cb's async global_load_lds DMA streams into Bs[cur^1] DURING the 9-tap
// compute on Bs[cur]; barrier's vmcnt drain is then ~free (loads had the whole
// compute phase in flight). 147KB -> 1 block/CU. NBUF=1 (conv2/3): r27 path.
// A/B lane maps: row/col = lane&31, k-group g = lane>>5; C/D map m74/m101.
template<int CIN, int COUT, int NBUF>
__global__ __launch_bounds__(448) void conv32(const f16* __restrict__ Xin,
                                              const f16* __restrict__ Wt,
                                              const float* __restrict__ bias,
                                              f16* __restrict__ Xout) {
    constexpr int NCB  = CIN / 32;
    constexpr int NCO  = COUT / 32;         // co-tiles per wave
    constexpr int NV_B = 9 * 4 * COUT;      // vec8 per cb panel
    constexpr int PT   = (NV_B + 447) / 448;
    __shared__ f16 Bs[NBUF][NV_B * 8];

    const int rg = blockIdx.x;          // rows rg*8 .. (rg==3: only 4 rows)
    const int b  = blockIdx.y;
    const int tid = threadIdx.x;
    const int w  = tid >> 6;            // wave = m-tile 0..6
    const int lane = tid & 63;
    const int lr = lane & 31;           // A row / B col within 32-tile
    const int g  = lane >> 5;           // k-subgroup
    const int PV = ((rg < 3) ? 8 : 4) * 28;   // valid px in block
    const int p  = w * 32 + lr;
    const int pc = (p < PV) ? p : 0;    // clamped (garbage rows never stored)
    const int yl = pc / 28, xx = pc - yl * 28;
    const int pixoff = (rg * 8 + yl) * 30 + xx;   // padded-coord pixel offset

    f32x16 acc[NCO];
    #pragma unroll
    for (int n = 0; n < NCO; ++n)
        #pragma unroll
        for (int r = 0; r < 16; ++r) acc[n][r] = 0.f;

    const size_t bbase = (size_t)b * NCB * 900;

    auto stage = [&](int cb, int buf) {
        #pragma unroll
        for (int pi = 0; pi < PT; ++pi) {
            const int v = tid + pi * 448;
            if (v < NV_B) {
                const int tap = v / (4 * COUT);
                const int w2  = v - tap * (4 * COUT);
                const f16* gsrc = Wt + ((size_t)(tap * NCB + cb) * (4 * COUT) + w2) * 8;
                f16* ldst = &Bs[buf][0] + (size_t)(pi * 448 + (tid & ~63)) * 8;
                __builtin_amdgcn_global_load_lds(
                    (const __attribute__((address_space(1))) void*)gsrc,
                    (__attribute__((address_space(3))) void*)ldst, 16, 0, 0);
            }
        }
    };
    auto compute = [&](int cb, int buf) {
        const f16* bp = &Bs[buf][0];
        #pragma unroll
        for (int tap = 0; tap < 9; ++tap) {
            const int dy = tap / 3, dx = tap - dy * 3;
            const size_t abase = (bbase + (size_t)cb * 900 + pixoff + dy * 30 + dx) * 32 + g * 8;
            const f16x8 a0 = ld8(Xin + abase);        // kh=0
            const f16x8 a1 = ld8(Xin + abase + 16);   // kh=1
            #pragma unroll
            for (int n = 0; n < NCO; ++n) {
                const f16x8 b0 = *reinterpret_cast<const f16x8*>(
                    bp + ((size_t)((tap * 4 + 0 * 2 + g) * COUT) + n * 32 + lr) * 8);
                const f16x8 b1 = *reinterpret_cast<const f16x8*>(
                    bp + ((size_t)((tap * 4 + 1 * 2 + g) * COUT) + n * 32 + lr) * 8);
                acc[n] = __builtin_amdgcn_mfma_f32_32x32x16_f16(a0, b0, acc[n], 0, 0, 0);
                acc[n] = __builtin_amdgcn_mfma_f32_32x32x16_f16(a1, b1, acc[n], 0, 0, 0);
            }
        }
    };

    if constexpr (NBUF == 2) {
        stage(0, 0);
        __syncthreads();
        int cur = 0;
        for (int cb = 0; cb < NCB; ++cb) {
            if (cb + 1 < NCB) stage(cb + 1, cur ^ 1);   // DMA in flight during compute
            compute(cb, cur);
            __syncthreads();                            // drains vmcnt: next panel ready
            cur ^= 1;
        }
    } else {
        for (int cb = 0; cb < NCB; ++cb) {
            stage(cb, 0);
            __syncthreads();
            compute(cb, 0);
            __syncthreads();
        }
    }

    // epilogue: col = n*32+lr, row = (r&3)+8*(r>>2)+4*g (m74/m101 layout)
    #pragma unroll
    for (int n = 0; n < NCO; ++n) {
        const int co = n * 32 + lr;
        const float bv = bias[co];
        #pragma unroll
        for (int r = 0; r < 16; ++r) {
            const int row = (r & 3) + 8 * (r >> 2) + 4 * g;
            const int pp = w * 32 + row;
            if (pp < PV) {
                const int yy = pp / 28, xo = pp - yy * 28;
                const size_t off = (((size_t)b * NCO + (co >> 5)) * 900 +
                                    (rg * 8 + yy + 1) * 30 + (xo + 1)) * 32 + (co & 31);
                Xout[off] = (f16)fmaxf(acc[n][r] + bv, 0.f);
            }
        }
    }
}

// ---------------- conv4: champion 16x16x32 template ----------------
template<int CIN, int COUT, int GM, int GN, int WNT, int MW, bool PADOUT>
__global__ __launch_bounds__(512) void conv3x3(const f16* __restrict__ Xin,
                                               const f16* __restrict__ Wt,
                                               const float* __restrict__ bias,
                                               f16* __restrict__ Xout) {
    constexpr int NCB  = CIN / 32;
    constexpr int NCBO = COUT / 32;
    constexpr int NV_B = 9 * 4 * COUT;
    constexpr int PT   = (NV_B + 511) / 512;
    __shared__ f16 Bs[NV_B * 8];

    const int rg = blockIdx.x;
    const int b  = blockIdx.y;
    const int tid = threadIdx.x;
    const int wave = tid >> 6;
    const int lane = tid & 63;
    const int lm = lane & 15, hi = lane >> 4;
    const int wm = wave % GM, wn = wave / GM;
    const int MT = (rg < 3) ? 14 : 7;

    f32x4 acc[MW][WNT];
    #pragma unroll
    for (int k = 0; k < MW; ++k)
        #pragma unroll
        for (int n = 0; n < WNT; ++n)
            acc[k][n] = (f32x4){0.f, 0.f, 0.f, 0.f};

    const size_t bbase = (size_t)b * NCB * 900;
    int inoff[MW];
    #pragma unroll
    for (int k = 0; k < MW; ++k) {
        const int m = wm + k * GM;
        const int p = m * 16 + lm;
        const int yl = p / 28, x = p - yl * 28;
        inoff[k] = (m < MT) ? ((rg * 8 + yl) * 30 + x) : 0;
    }

    for (int cb = 0; cb < NCB; ++cb) {
        #pragma unroll
        for (int pi = 0; pi < PT; ++pi) {
            const int v = tid + pi * 512;
            if (v < NV_B) {
                const int tap = v / (4 * COUT);
                const int w   = v - tap * (4 * COUT);
                const f16* gsrc = Wt + ((size_t)(tap * NCB + cb) * (4 * COUT) + w) * 8;
                f16* ldst = Bs + (size_t)(pi * 512 + (tid & ~63)) * 8;
                __builtin_amdgcn_global_load_lds(
                    (const __attribute__((address_space(1))) void*)gsrc,
                    (__attribute__((address_space(3))) void*)ldst, 16, 0, 0);
            }
        }
        __syncthreads();

        #pragma unroll
        for (int tap = 0; tap < 9; ++tap) {
            f16x8 bf[WNT];
            #pragma unroll
            for (int n = 0; n < WNT; ++n)
                bf[n] = *reinterpret_cast<const f16x8*>(
                    Bs + ((size_t)(tap * 4 + hi) * COUT + (wn * WNT + n) * 16 + lm) * 8);
            const int dy = tap / 3, dx = tap - dy * 3;
            const size_t dOff = (bbase + (size_t)cb * 900 + dy * 30 + dx) * 32 + hi * 8;
            #pragma unroll
            for (int k = 0; k < MW; ++k) {
                if (wm + k * GM < MT) {
                    const f16x8 af = ld8(Xin + dOff + (size_t)inoff[k] * 32);
                    #pragma unroll
                    for (int n = 0; n < WNT; ++n)
                        acc[k][n] = __builtin_amdgcn_mfma_f32_16x16x32_f16(af, bf[n], acc[k][n], 0, 0, 0);
                }
            }
        }
        __syncthreads();
    }

    #pragma unroll
    for (int k = 0; k < MW; ++k) {
        const int m = wm + k * GM;
        if (m < MT) {
            #pragma unroll
            for (int n = 0; n < WNT; ++n) {
                const int co = (wn * WNT + n) * 16 + lm;
                const float bv = bias[co];
                #pragma unroll
                for (int r = 0; r < 4; ++r) {
                    const int p = m * 16 + hi * 4 + r;
                    const int yl = p / 28, x = p - yl * 28;
                    const float v = fmaxf(acc[k][n][r] + bv, 0.f);
                    size_t off;
                    if (PADOUT)
                        off = (((size_t)b * NCBO + (co >> 5)) * 900 +
                               (rg * 8 + yl + 1) * 30 + (x + 1)) * 32 + (co & 31);
                    else
                        off = ((size_t)b * 784 + (rg * 8 + yl) * 28 + x) * COUT + co;
                    Xout[off] = (f16)v;
                }
            }
        }
    }
}

// ---------------- FC layers ----------------
__global__ __launch_bounds__(256) void fc1k(const f16* __restrict__ X4,
                                            const f16* __restrict__ FW1t,
                                            const float* __restrict__ fb1,
                                            f16* __restrict__ X5, int CH) {
    const int bm = blockIdx.x;
    const int nt = blockIdx.y * 4 + (threadIdx.x >> 6);
    const int lane = threadIdx.x & 63;
    const int lm = lane & 15, hi = lane >> 4;
    f32x4 acc = (f32x4){0.f, 0.f, 0.f, 0.f};
    const int row0 = bm * 16 + lm;
    const int rowA = (row0 < CH) ? row0 : 0;
    const f16* arow = X4 + (size_t)rowA * 12544;
    const int o = nt * 16 + lm;
    const f16* brow = FW1t + (size_t)o * 12544;
    for (int kk = 0; kk < 12544; kk += 32) {
        const f16x8 af = ld8(arow + kk + hi * 8);
        const f16x8 bf = ld8(brow + kk + hi * 8);
        acc = __builtin_amdgcn_mfma_f32_16x16x32_f16(af, bf, acc, 0, 0, 0);
    }
    const float bv = fb1[o];
    #pragma unroll
    for (int r = 0; r < 4; ++r) {
        const int row = bm * 16 + hi * 4 + r;
        if (row < CH)
            X5[(size_t)row * 256 + o] = (f16)fmaxf(acc[r] + bv, 0.f);
    }
}

__global__ void fc2k(const f16* __restrict__ X5, const float* __restrict__ fw2,
                     const float* __restrict__ fb2, float* __restrict__ out, int CH) {
    int t = blockIdx.x * 256 + threadIdx.x;
    if (t < CH * 24) {
        int b = t / 24, o = t % 24;
        float s = fb2[o];
        const f16* xr = X5 + (size_t)b * 256;
        const float* wr = fw2 + (size_t)o * 256;
        for (int k = 0; k < 256; ++k) s += (float)xr[k] * wr[k];
        if (o == 2 || o == 3) s = 1.f / (1.f + expf(-s));
        out[t] = s;
    }
}

// ---------------- launch ----------------
extern "C" void kernel_launch(void* const* d_in, const int* in_sizes, int n_in,
                              void* d_out, int out_size, void* d_ws, size_t ws_size,
                              hipStream_t stream) {
    const float* image    = (const float*)d_in[0];
    const float* features = (const float*)d_in[1];
    const float* centers  = (const float*)d_in[2];
    const float* w1  = (const float*)d_in[3];
    const float* b1  = (const float*)d_in[4];
    const float* w2  = (const float*)d_in[5];
    const float* b2  = (const float*)d_in[6];
    const float* w3  = (const float*)d_in[7];
    const float* b3  = (const float*)d_in[8];
    const float* w4  = (const float*)d_in[9];
    const float* b4  = (const float*)d_in[10];
    const float* fw1 = (const float*)d_in[11];
    const float* fb1 = (const float*)d_in[12];
    const float* fw2 = (const float*)d_in[13];
    const float* fb2 = (const float*)d_in[14];

    // pick largest chunk (batches per pass) that fits ws_size; CH divides 256
    int CH = 8;
    for (int c = 256; c >= 8; c >>= 1) {
        if (WEIGHTS_B + (size_t)c * PER_BATCH <= ws_size) { CH = c; break; }
    }

    char* ws = (char*)d_ws;
    f16* W1t  = (f16*)(ws);
    f16* W2t  = (f16*)(ws + W1T_B);
    f16* W3t  = (f16*)(ws + W1T_B + W2T_B);
    f16* W4t  = (f16*)(ws + W1T_B + W2T_B + W3T_B);
    f16* FW1t = (f16*)(ws + W1T_B + W2T_B + W3T_B + W4T_B);
    char* act = ws + WEIGHTS_B;
    f16* X0 = (f16*)(act);
    f16* X1 = (f16*)(act + (size_t)CH * PB_X0);
    f16* X2 = (f16*)(act + (size_t)CH * (PB_X0 + PB_X1));
    f16* X3 = (f16*)(act + (size_t)CH * (PB_X0 + PB_X1 + PB_X2));
    f16* X4 = (f16*)(act + (size_t)CH * (PB_X0 + PB_X1 + PB_X2 + PB_X3));
    f16* X5 = (f16*)(act + (size_t)CH * (PB_X0 + PB_X1 + PB_X2 + PB_X3 + PB_X4));

    prep_all<<<(PREP_TOT + 255) / 256, 256, 0, stream>>>(w1, w2, w3, w4, fw1,
                                                         W1t, W2t, W3t, W4t, FW1t);

    for (int b0 = 0; b0 < 256; b0 += CH) {
        build_x0<<<CH, 512, 0, stream>>>(image, features, centers,
                                         X0, X1, X2, X3, b0);

        dim3 cgrid(4, CH);
        conv32<544, 128, 2><<<cgrid, 448, 0, stream>>>(X0, W1t, b1, X1);
        conv32<128, 64,  1><<<cgrid, 448, 0, stream>>>(X1, W2t, b2, X2);
        conv32<64,  32,  1><<<cgrid, 448, 0, stream>>>(X2, W3t, b3, X3);
        conv3x3<32, 16, 8, 1, 1, 2, false><<<cgrid, 512, 0, stream>>>(X3, W4t, b4, X4);

        dim3 fgrid((CH + 15) / 16, 4);
        fc1k<<<fgrid, 256, 0, stream>>>(X4, FW1t, fb1, X5, CH);
        fc2k<<<(CH * 24 + 255) / 256, 256, 0, stream>>>(X5, fw2, fb2,
                                                        (float*)d_out + (size_t)b0 * 24, CH);
    }
}

// Round 29
// 767.332 us; speedup vs baseline: 1.0088x; 1.0088x over previous
//
#include <hip/hip_runtime.h>

typedef _Float16 f16;
typedef _Float16 f16x8 __attribute__((ext_vector_type(8)));
typedef float    f32x4 __attribute__((ext_vector_type(4)));
typedef float    f32x16 __attribute__((ext_vector_type(16)));

static __device__ __forceinline__ f16x8 ld8(const f16* p) {
    return *reinterpret_cast<const f16x8*>(p);
}

// ---------------- ws layout (bytes) ----------------
// Activations are CHUNK-BLOCKED: [b][cb][30][30][32] f16 (cb = channel/32).
static constexpr size_t W1T_B  = 1253376;  // 9*17*4*128*8 f16 (32x32 layout)
static constexpr size_t W2T_B  = 147456;   // 9*4*4*64*8  (32x32 layout)
static constexpr size_t W3T_B  = 36864;    // 9*2*4*32*8  (32x32 layout)
static constexpr size_t W4T_B  = 9216;     // 9*1*4*16*8  (16x16 layout)
static constexpr size_t FW1T_B = 6422528;  // 256*12544 f16
static constexpr size_t WEIGHTS_B = W1T_B + W2T_B + W3T_B + W4T_B + FW1T_B; // 7,869,440

static constexpr size_t PB_X0 = 979200;    // 17 chunks * 900 * 32 f16
static constexpr size_t PB_X1 = 230400;    // 4 chunks
static constexpr size_t PB_X2 = 115200;    // 2 chunks
static constexpr size_t PB_X3 = 57600;     // 1 chunk
static constexpr size_t PB_X4 = 25088;     // 28*28*16 flat (fc1 k-order)
static constexpr size_t PB_X5 = 512;       // 256 f16
static constexpr size_t PER_BATCH = PB_X0 + PB_X1 + PB_X2 + PB_X3 + PB_X4 + PB_X5; // 1,408,000

// ---------------- merged weight prep (one dispatch) ----------------
// 16x16 layout (conv4): [tap][cb][hi][co][j8], ci = cb*32 + hi*8 + j
static __device__ __forceinline__ void wxf(const float* __restrict__ w, f16* __restrict__ wt,
                                           int i, int CINr, int NCB, int COUT) {
    int co = i % COUT;
    int r  = i / COUT;
    int hi = r & 3; r >>= 2;
    int cb = r % NCB;
    int tap = r / NCB;
    f16x8 v;
    #pragma unroll
    for (int j = 0; j < 8; ++j) {
        int ci = cb * 32 + hi * 8 + j;
        float x = (ci < CINr) ? w[((size_t)co * CINr + ci) * 9 + tap] : 0.f;
        v[j] = (f16)x;
    }
    *reinterpret_cast<f16x8*>(wt + (size_t)i * 8) = v;
}

// 32x32x16 layout (conv1-3): [tap][cb][kh(2)][g(2)][co][j8],
// ci = cb*32 + kh*16 + g*8 + j  (g = lane>>5 k-subgroup; pairing positional)
static __device__ __forceinline__ void wxf32g(const float* __restrict__ w,
                                              f16* __restrict__ wt, int i,
                                              int CINr, int NCB, int COUT) {
    int co = i % COUT;
    int r  = i / COUT;
    int g  = r & 1; r >>= 1;
    int kh = r & 1; r >>= 1;
    int cb = r % NCB;
    int tap = r / NCB;
    f16x8 v;
    #pragma unroll
    for (int j = 0; j < 8; ++j) {
        int ci = cb * 32 + kh * 16 + g * 8 + j;
        float x = (ci < CINr) ? w[((size_t)co * CINr + ci) * 9 + tap] : 0.f;
        v[j] = (f16)x;
    }
    *reinterpret_cast<f16x8*>(wt + (size_t)i * 8) = v;
}

static constexpr int S1 = 9 * 17 * 4 * 128;   // 78336 vec8 items
static constexpr int S2 = 9 * 4  * 4 * 64;    // 9216
static constexpr int S3 = 9 * 2  * 4 * 32;    // 2304
static constexpr int S4 = 9 * 1  * 4 * 16;    // 576
static constexpr int SW = S1 + S2 + S3 + S4;  // 90432
static constexpr int SFW = 256 * 12544;       // 3211264 scalar f16
static constexpr int PREP_TOT = SW + SFW;

__global__ void prep_all(const float* __restrict__ w1, const float* __restrict__ w2,
                         const float* __restrict__ w3, const float* __restrict__ w4,
                         const float* __restrict__ fw1,
                         f16* __restrict__ W1t, f16* __restrict__ W2t,
                         f16* __restrict__ W3t, f16* __restrict__ W4t,
                         f16* __restrict__ FW1t) {
    int t = blockIdx.x * 256 + threadIdx.x;
    if (t >= PREP_TOT) return;
    if (t < S1) { wxf32g(w1, W1t, t, 516, 17, 128); return; }
    t -= S1;
    if (t < S2) { wxf32g(w2, W2t, t, 128, 4, 64); return; }
    t -= S2;
    if (t < S3) { wxf32g(w3, W3t, t, 64, 2, 32); return; }
    t -= S3;
    if (t < S4) { wxf(w4, W4t, t, 32, 1, 16); return; }
    t -= S4;
    // fw1t[o][y*448 + x*16 + c] = fw1[o][c*784 + y*28 + x]  (k-order matches X4 flat)
    int o = t / 12544, idx = t % 12544;
    int y = idx / 448, rem = idx % 448;
    int x = rem / 16, c = rem & 15;
    FW1t[t] = (f16)fw1[(size_t)o * 12544 + c * 784 + y * 28 + x];
}

// ---------------- fused X0/ring builder (chunk-blocked): one block per batch ----------------
static __device__ __forceinline__ void ring_yx(int bi, int& y, int& x) {
    // 116 border pixels of a 30x30 tile
    if (bi < 30)      { y = 0;        x = bi; }
    else if (bi < 60) { y = 29;       x = bi - 30; }
    else if (bi < 88) { y = bi - 59;  x = 0; }      // 1..28
    else              { y = bi - 87;  x = 29; }     // 1..28
}

__global__ __launch_bounds__(512) void build_x0(
        const float* __restrict__ img, const float* __restrict__ feat,
        const float* __restrict__ centers,
        f16* __restrict__ X0, f16* __restrict__ X1,
        f16* __restrict__ X2, f16* __restrict__ X3, int b0) {
    const int bl = blockIdx.x;            // chunk-local batch
    const int b  = b0 + bl;               // global batch
    const int tid = threadIdx.x;
    f16* x0b = X0 + (size_t)bl * (17 * 900 * 32);

    // (a) X0 border ring, all 544 ch  (chunk cb=c>>5, lane c&31)
    for (int i = tid; i < 116 * 544; i += 512) {
        int c = i % 544, bi = i / 544;
        int y, x; ring_yx(bi, y, x);
        x0b[((size_t)(c >> 5) * 900 + y * 30 + x) * 32 + (c & 31)] = (f16)0.f;
    }
    // (b) cmap plane interior zero (ch 515 -> chunk 16, lane 3)
    for (int i = tid; i < 784; i += 512) {
        int y = i / 28, x = i % 28;
        x0b[((size_t)16 * 900 + (y + 1) * 30 + x + 1) * 32 + 3] = (f16)0.f;
    }
    // (c) image fill (ch 0..2 -> chunk 0)
    for (int i = tid; i < 3 * 784; i += 512) {
        int c = i / 784, p = i % 784;
        int y = p / 28, x = p % 28;
        x0b[((size_t)(y + 1) * 30 + x + 1) * 32 + c] =
            (f16)img[((size_t)b * 3 + c) * 784 + p];
    }
    // (d) bilinear 7x7 -> 28x28; tid = feat channel, maps to ch tid+3
    {
        const int c  = tid + 3;
        const int cb = c >> 5, c32 = c & 31;
        const float* fb = feat + ((size_t)b * 512 + tid) * 49;
        float r0[7], r1[7];
        int cur = -100;
        for (int y = 0; y < 28; ++y) {
            float sy = (y + 0.5f) * 0.25f - 0.5f;
            float fy = floorf(sy);
            int iy0 = (int)fy;
            float wy1 = sy - fy, wy0 = 1.f - wy1;
            if (iy0 != cur) {
                cur = iy0;
                int i0 = iy0 < 0 ? 0 : iy0;
                int i1 = (iy0 + 1 > 6) ? 6 : iy0 + 1;
                #pragma unroll
                for (int j = 0; j < 7; ++j) { r0[j] = fb[i0 * 7 + j]; r1[j] = fb[i1 * 7 + j]; }
            }
            f16* orow = x0b + ((size_t)cb * 900 + (y + 1) * 30 + 1) * 32 + c32;
            #pragma unroll 28
            for (int x = 0; x < 28; ++x) {
                float sx = (x + 0.5f) * 0.25f - 0.5f;
                float fx = floorf(sx);
                int ix0 = (int)fx;
                float wx1 = sx - fx, wx0 = 1.f - wx1;
                int j0 = ix0 < 0 ? 0 : ix0;
                int j1 = (ix0 + 1 > 6) ? 6 : ix0 + 1;
                float v = wy0 * (wx0 * r0[j0] + wx1 * r0[j1]) +
                          wy1 * (wx0 * r1[j0] + wx1 * r1[j1]);
                orow[(size_t)x * 32] = (f16)v;
            }
        }
    }
    // (e) X1/X2/X3 border rings (chunk-blocked)
    {
        f16* x1b = X1 + (size_t)bl * (4 * 900 * 32);
        for (int i = tid; i < 116 * 128; i += 512) {
            int c = i % 128, bi = i / 128;
            int y, x; ring_yx(bi, y, x);
            x1b[((size_t)(c >> 5) * 900 + y * 30 + x) * 32 + (c & 31)] = (f16)0.f;
        }
        f16* x2b = X2 + (size_t)bl * (2 * 900 * 32);
        for (int i = tid; i < 116 * 64; i += 512) {
            int c = i % 64, bi = i / 64;
            int y, x; ring_yx(bi, y, x);
            x2b[((size_t)(c >> 5) * 900 + y * 30 + x) * 32 + (c & 31)] = (f16)0.f;
        }
        f16* x3b = X3 + (size_t)bl * (900 * 32);
        for (int i = tid; i < 116 * 32; i += 512) {
            int c = i % 32, bi = i / 32;
            int y, x; ring_yx(bi, y, x);
            x3b[((size_t)y * 30 + x) * 32 + c] = (f16)0.f;
        }
    }
    __syncthreads();
    // (f) sequential scatter, last-write-wins (matches np order); ch 515 -> chunk16 lane3
    if (tid == 0) {
        const float* cb = centers + (size_t)b * 400;
        for (int n = 0; n < 100; ++n) {
            float cx = cb[n * 4 + 0], cy = cb[n * 4 + 1], conf = cb[n * 4 + 3];
            int xp = (int)(cx * 28.f);
            int yp = (int)(cy * 28.f);
            if (xp >= 0 && xp < 28 && yp >= 0 && yp < 28)
                x0b[((size_t)16 * 900 + (yp + 1) * 30 + xp + 1) * 32 + 3] = (f16)conf;
        }
    }
}

// ---------------- conv1-3: 32x32x16 MFMA template ----------------
// 8-row blocks = 224 px = 7 m-tiles of 32 -> 7 waves (448 thr), each wave
// owns 1 m-tile x NCO co-tiles. NBUF=2 (conv1): HALF-PANEL double-buffer --
// the panel splits exactly along kh (each half: 9 taps x 1 A-load x NCO MFMAs),
// so Bs[2][9*2*COUT] totals the SAME 73.7KB as single-buffer -> 2 blocks/CU
// co-residency preserved (r28's 147KB full-dbuf lost it and regressed).
// Half h+1's async DMA streams during half h's compute; barrier drain ~free.
// A/B lane maps: row/col = lane&31, g = lane>>5; C/D map m74/m101.
template<int CIN, int COUT, int NBUF>
__global__ __launch_bounds__(448) void conv32(const f16* __restrict__ Xin,
                                              const f16* __restrict__ Wt,
                                              const float* __restrict__ bias,
                                              f16* __restrict__ Xout) {
    constexpr int NCB  = CIN / 32;
    constexpr int NCO  = COUT / 32;         // co-tiles per wave
    constexpr int NV_B = 9 * 4 * COUT;      // vec8 per full cb panel
    constexpr int NV_H = 9 * 2 * COUT;      // vec8 per kh-half panel
    constexpr int PT   = (NV_B + 447) / 448;
    constexpr int PTH  = (NV_H + 447) / 448;
    constexpr int BUFV = (NBUF == 2) ? NV_H : NV_B;
    __shared__ f16 Bs[NBUF][BUFV * 8];      // both cases: 73,728 B total (COUT=128)

    const int rg = blockIdx.x;          // rows rg*8 .. (rg==3: only 4 rows)
    const int b  = blockIdx.y;
    const int tid = threadIdx.x;
    const int w  = tid >> 6;            // wave = m-tile 0..6
    const int lane = tid & 63;
    const int lr = lane & 31;           // A row / B col within 32-tile
    const int g  = lane >> 5;           // k-subgroup
    const int PV = ((rg < 3) ? 8 : 4) * 28;   // valid px in block
    const int p  = w * 32 + lr;
    const int pc = (p < PV) ? p : 0;    // clamped (garbage rows never stored)
    const int yl = pc / 28, xx = pc - yl * 28;
    const int pixoff = (rg * 8 + yl) * 30 + xx;   // padded-coord pixel offset

    f32x16 acc[NCO];
    #pragma unroll
    for (int n = 0; n < NCO; ++n)
        #pragma unroll
        for (int r = 0; r < 16; ++r) acc[n][r] = 0.f;

    const size_t bbase = (size_t)b * NCB * 900;

    // ---- full-panel path (NBUF == 1) ----
    auto stage_full = [&](int cb) {
        #pragma unroll
        for (int pi = 0; pi < PT; ++pi) {
            const int v = tid + pi * 448;
            if (v < NV_B) {
                const int tap = v / (4 * COUT);
                const int w2  = v - tap * (4 * COUT);
                const f16* gsrc = Wt + ((size_t)(tap * NCB + cb) * (4 * COUT) + w2) * 8;
                f16* ldst = &Bs[0][0] + (size_t)(pi * 448 + (tid & ~63)) * 8;
                __builtin_amdgcn_global_load_lds(
                    (const __attribute__((address_space(1))) void*)gsrc,
                    (__attribute__((address_space(3))) void*)ldst, 16, 0, 0);
            }
        }
    };
    auto compute_full = [&](int cb) {
        const f16* bp = &Bs[0][0];
        #pragma unroll
        for (int tap = 0; tap < 9; ++tap) {
            const int dy = tap / 3, dx = tap - dy * 3;
            const size_t abase = (bbase + (size_t)cb * 900 + pixoff + dy * 30 + dx) * 32 + g * 8;
            const f16x8 a0 = ld8(Xin + abase);        // kh=0
            const f16x8 a1 = ld8(Xin + abase + 16);   // kh=1
            #pragma unroll
            for (int n = 0; n < NCO; ++n) {
                const f16x8 b0 = *reinterpret_cast<const f16x8*>(
                    bp + ((size_t)((tap * 4 + 0 * 2 + g) * COUT) + n * 32 + lr) * 8);
                const f16x8 b1 = *reinterpret_cast<const f16x8*>(
                    bp + ((size_t)((tap * 4 + 1 * 2 + g) * COUT) + n * 32 + lr) * 8);
                acc[n] = __builtin_amdgcn_mfma_f32_32x32x16_f16(a0, b0, acc[n], 0, 0, 0);
                acc[n] = __builtin_amdgcn_mfma_f32_32x32x16_f16(a1, b1, acc[n], 0, 0, 0);
            }
        }
    };

    // ---- half-panel dbuf path (NBUF == 2); half = (cb, kh) ----
    // LDS half layout: [tap][g][co] (linear); global source strided per tap.
    auto stage_half = [&](int cb, int kh, int buf) {
        #pragma unroll
        for (int pi = 0; pi < PTH; ++pi) {
            const int v = tid + pi * 448;
            if (v < NV_H) {
                const int tap = v / (2 * COUT);
                const int rem = v - tap * (2 * COUT);   // g*COUT + co
                const f16* gsrc = Wt +
                    ((size_t)((tap * NCB + cb) * 4 + kh * 2) * COUT + rem) * 8;
                f16* ldst = &Bs[buf][0] + (size_t)(pi * 448 + (tid & ~63)) * 8;
                __builtin_amdgcn_global_load_lds(
                    (const __attribute__((address_space(1))) void*)gsrc,
                    (__attribute__((address_space(3))) void*)ldst, 16, 0, 0);
            }
        }
    };
    auto compute_half = [&](int cb, int kh, int buf) {
        const f16* bp = &Bs[buf][0];
        #pragma unroll
        for (int tap = 0; tap < 9; ++tap) {
            const int dy = tap / 3, dx = tap - dy * 3;
            const size_t abase = (bbase + (size_t)cb * 900 + pixoff + dy * 30 + dx) * 32
                                 + kh * 16 + g * 8;
            const f16x8 a = ld8(Xin + abase);
            #pragma unroll
            for (int n = 0; n < NCO; ++n) {
                const f16x8 bb = *reinterpret_cast<const f16x8*>(
                    bp + ((size_t)((tap * 2 + g) * COUT) + n * 32 + lr) * 8);
                acc[n] = __builtin_amdgcn_mfma_f32_32x32x16_f16(a, bb, acc[n], 0, 0, 0);
            }
        }
    };

    if constexpr (NBUF == 2) {
        stage_half(0, 0, 0);
        __syncthreads();
        int cur = 0;
        for (int h = 0; h < NCB * 2; ++h) {
            const int nh = h + 1;
            if (nh < NCB * 2) stage_half(nh >> 1, nh & 1, cur ^ 1);  // DMA over compute
            compute_half(h >> 1, h & 1, cur);
            __syncthreads();               // drains vmcnt: next half ready
            cur ^= 1;
        }
    } else {
        for (int cb = 0; cb < NCB; ++cb) {
            stage_full(cb);
            __syncthreads();
            compute_full(cb);
            __syncthreads();
        }
    }

    // epilogue: col = n*32+lr, row = (r&3)+8*(r>>2)+4*g (m74/m101 layout)
    #pragma unroll
    for (int n = 0; n < NCO; ++n) {
        const int co = n * 32 + lr;
        const float bv = bias[co];
        #pragma unroll
        for (int r = 0; r < 16; ++r) {
            const int row = (r & 3) + 8 * (r >> 2) + 4 * g;
            const int pp = w * 32 + row;
            if (pp < PV) {
                const int yy = pp / 28, xo = pp - yy * 28;
                const size_t off = (((size_t)b * NCO + (co >> 5)) * 900 +
                                    (rg * 8 + yy + 1) * 30 + (xo + 1)) * 32 + (co & 31);
                Xout[off] = (f16)fmaxf(acc[n][r] + bv, 0.f);
            }
        }
    }
}

// ---------------- conv4: champion 16x16x32 template ----------------
template<int CIN, int COUT, int GM, int GN, int WNT, int MW, bool PADOUT>
__global__ __launch_bounds__(512) void conv3x3(const f16* __restrict__ Xin,
                                               const f16* __restrict__ Wt,
                                               const float* __restrict__ bias,
                                               f16* __restrict__ Xout) {
    constexpr int NCB  = CIN / 32;
    constexpr int NCBO = COUT / 32;
    constexpr int NV_B = 9 * 4 * COUT;
    constexpr int PT   = (NV_B + 511) / 512;
    __shared__ f16 Bs[NV_B * 8];

    const int rg = blockIdx.x;
    const int b  = blockIdx.y;
    const int tid = threadIdx.x;
    const int wave = tid >> 6;
    const int lane = tid & 63;
    const int lm = lane & 15, hi = lane >> 4;
    const int wm = wave % GM, wn = wave / GM;
    const int MT = (rg < 3) ? 14 : 7;

    f32x4 acc[MW][WNT];
    #pragma unroll
    for (int k = 0; k < MW; ++k)
        #pragma unroll
        for (int n = 0; n < WNT; ++n)
            acc[k][n] = (f32x4){0.f, 0.f, 0.f, 0.f};

    const size_t bbase = (size_t)b * NCB * 900;
    int inoff[MW];
    #pragma unroll
    for (int k = 0; k < MW; ++k) {
        const int m = wm + k * GM;
        const int p = m * 16 + lm;
        const int yl = p / 28, x = p - yl * 28;
        inoff[k] = (m < MT) ? ((rg * 8 + yl) * 30 + x) : 0;
    }

    for (int cb = 0; cb < NCB; ++cb) {
        #pragma unroll
        for (int pi = 0; pi < PT; ++pi) {
            const int v = tid + pi * 512;
            if (v < NV_B) {
                const int tap = v / (4 * COUT);
                const int w   = v - tap * (4 * COUT);
                const f16* gsrc = Wt + ((size_t)(tap * NCB + cb) * (4 * COUT) + w) * 8;
                f16* ldst = Bs + (size_t)(pi * 512 + (tid & ~63)) * 8;
                __builtin_amdgcn_global_load_lds(
                    (const __attribute__((address_space(1))) void*)gsrc,
                    (__attribute__((address_space(3))) void*)ldst, 16, 0, 0);
            }
        }
        __syncthreads();

        #pragma unroll
        for (int tap = 0; tap < 9; ++tap) {
            f16x8 bf[WNT];
            #pragma unroll
            for (int n = 0; n < WNT; ++n)
                bf[n] = *reinterpret_cast<const f16x8*>(
                    Bs + ((size_t)(tap * 4 + hi) * COUT + (wn * WNT + n) * 16 + lm) * 8);
            const int dy = tap / 3, dx = tap - dy * 3;
            const size_t dOff = (bbase + (size_t)cb * 900 + dy * 30 + dx) * 32 + hi * 8;
            #pragma unroll
            for (int k = 0; k < MW; ++k) {
                if (wm + k * GM < MT) {
                    const f16x8 af = ld8(Xin + dOff + (size_t)inoff[k] * 32);
                    #pragma unroll
                    for (int n = 0; n < WNT; ++n)
                        acc[k][n] = __builtin_amdgcn_mfma_f32_16x16x32_f16(af, bf[n], acc[k][n], 0, 0, 0);
                }
            }
        }
        __syncthreads();
    }

    #pragma unroll
    for (int k = 0; k < MW; ++k) {
        const int m = wm + k * GM;
        if (m < MT) {
            #pragma unroll
            for (int n = 0; n < WNT; ++n) {
                const int co = (wn * WNT + n) * 16 + lm;
                const float bv = bias[co];
                #pragma unroll
                for (int r = 0; r < 4; ++r) {
                    const int p = m * 16 + hi * 4 + r;
                    const int yl = p / 28, x = p - yl * 28;
                    const float v = fmaxf(acc[k][n][r] + bv, 0.f);
                    size_t off;
                    if (PADOUT)
                        off = (((size_t)b * NCBO + (co >> 5)) * 900 +
                               (rg * 8 + yl + 1) * 30 + (x + 1)) * 32 + (co & 31);
                    else
                        off = ((size_t)b * 784 + (rg * 8 + yl) * 28 + x) * COUT + co;
                    Xout[off] = (f16)v;
                }
            }
        }
    }
}

// ---------------- FC layers ----------------
__global__ __launch_bounds__(256) void fc1k(const f16* __restrict__ X4,
                                            const f16* __restrict__ FW1t,
                                            const float* __restrict__ fb1,
                                            f16* __restrict__ X5, int CH) {
    const int bm = blockIdx.x;
    const int nt = blockIdx.y * 4 + (threadIdx.x >> 6);
    const int lane = threadIdx.x & 63;
    const int lm = lane & 15, hi = lane >> 4;
    f32x4 acc = (f32x4){0.f, 0.f, 0.f, 0.f};
    const int row0 = bm * 16 + lm;
    const int rowA = (row0 < CH) ? row0 : 0;
    const f16* arow = X4 + (size_t)rowA * 12544;
    const int o = nt * 16 + lm;
    const f16* brow = FW1t + (size_t)o * 12544;
    for (int kk = 0; kk < 12544; kk += 32) {
        const f16x8 af = ld8(arow + kk + hi * 8);
        const f16x8 bf = ld8(brow + kk + hi * 8);
        acc = __builtin_amdgcn_mfma_f32_16x16x32_f16(af, bf, acc, 0, 0, 0);
    }
    const float bv = fb1[o];
    #pragma unroll
    for (int r = 0; r < 4; ++r) {
        const int row = bm * 16 + hi * 4 + r;
        if (row < CH)
            X5[(size_t)row * 256 + o] = (f16)fmaxf(acc[r] + bv, 0.f);
    }
}

__global__ void fc2k(const f16* __restrict__ X5, const float* __restrict__ fw2,
                     const float* __restrict__ fb2, float* __restrict__ out, int CH) {
    int t = blockIdx.x * 256 + threadIdx.x;
    if (t < CH * 24) {
        int b = t / 24, o = t % 24;
        float s = fb2[o];
        const f16* xr = X5 + (size_t)b * 256;
        const float* wr = fw2 + (size_t)o * 256;
        for (int k = 0; k < 256; ++k) s += (float)xr[k] * wr[k];
        if (o == 2 || o == 3) s = 1.f / (1.f + expf(-s));
        out[t] = s;
    }
}

// ---------------- launch ----------------
extern "C" void kernel_launch(void* const* d_in, const int* in_sizes, int n_in,
                              void* d_out, int out_size, void* d_ws, size_t ws_size,
                              hipStream_t stream) {
    const float* image    = (const float*)d_in[0];
    const float* features = (const float*)d_in[1];
    const float* centers  = (const float*)d_in[2];
    const float* w1  = (const float*)d_in[3];
    const float* b1  = (const float*)d_in[4];
    const float* w2  = (const float*)d_in[5];
    const float* b2  = (const float*)d_in[6];
    const float* w3  = (const float*)d_in[7];
    const float* b3  = (const float*)d_in[8];
    const float* w4  = (const float*)d_in[9];
    const float* b4  = (const float*)d_in[10];
    const float* fw1 = (const float*)d_in[11];
    const float* fb1 = (const float*)d_in[12];
    const float* fw2 = (const float*)d_in[13];
    const float* fb2 = (const float*)d_in[14];

    // pick largest chunk (batches per pass) that fits ws_size; CH divides 256
    int CH = 8;
    for (int c = 256; c >= 8; c >>= 1) {
        if (WEIGHTS_B + (size_t)c * PER_BATCH <= ws_size) { CH = c; break; }
    }

    char* ws = (char*)d_ws;
    f16* W1t  = (f16*)(ws);
    f16* W2t  = (f16*)(ws + W1T_B);
    f16* W3t  = (f16*)(ws + W1T_B + W2T_B);
    f16* W4t  = (f16*)(ws + W1T_B + W2T_B + W3T_B);
    f16* FW1t = (f16*)(ws + W1T_B + W2T_B + W3T_B + W4T_B);
    char* act = ws + WEIGHTS_B;
    f16* X0 = (f16*)(act);
    f16* X1 = (f16*)(act + (size_t)CH * PB_X0);
    f16* X2 = (f16*)(act + (size_t)CH * (PB_X0 + PB_X1));
    f16* X3 = (f16*)(act + (size_t)CH * (PB_X0 + PB_X1 + PB_X2));
    f16* X4 = (f16*)(act + (size_t)CH * (PB_X0 + PB_X1 + PB_X2 + PB_X3));
    f16* X5 = (f16*)(act + (size_t)CH * (PB_X0 + PB_X1 + PB_X2 + PB_X3 + PB_X4));

    prep_all<<<(PREP_TOT + 255) / 256, 256, 0, stream>>>(w1, w2, w3, w4, fw1,
                                                         W1t, W2t, W3t, W4t, FW1t);

    for (int b0 = 0; b0 < 256; b0 += CH) {
        build_x0<<<CH, 512, 0, stream>>>(image, features, centers,
                                         X0, X1, X2, X3, b0);

        dim3 cgrid(4, CH);
        conv32<544, 128, 2><<<cgrid, 448, 0, stream>>>(X0, W1t, b1, X1);
        conv32<128, 64,  1><<<cgrid, 448, 0, stream>>>(X1, W2t, b2, X2);
        conv32<64,  32,  1><<<cgrid, 448, 0, stream>>>(X2, W3t, b3, X3);
        conv3x3<32, 16, 8, 1, 1, 2, false><<<cgrid, 512, 0, stream>>>(X3, W4t, b4, X4);

        dim3 fgrid((CH + 15) / 16, 4);
        fc1k<<<fgrid, 256, 0, stream>>>(X4, FW1t, fb1, X5, CH);
        fc2k<<<(CH * 24 + 255) / 256, 256, 0, stream>>>(X5, fw2, fb2,
                                                        (float*)d_out + (size_t)b0 * 24, CH);
    }
}

// Round 30
// 737.481 us; speedup vs baseline: 1.0496x; 1.0405x over previous
//
#include <hip/hip_runtime.h>

typedef _Float16 f16;
typedef _Float16 f16x8 __attribute__((ext_vector_type(8)));
typedef float    f32x4 __attribute__((ext_vector_type(4)));
typedef float    f32x16 __attribute__((ext_vector_type(16)));

static __device__ __forceinline__ f16x8 ld8(const f16* p) {
    return *reinterpret_cast<const f16x8*>(p);
}

// ---------------- ws layout (bytes) ----------------
// Activations are CHUNK-BLOCKED: [b][cb][30][30][32] f16 (cb = channel/32).
static constexpr size_t W1T_B  = 1253376;  // 9*17*4*128*8 f16 (32x32 layout)
static constexpr size_t W2T_B  = 147456;   // 9*4*4*64*8  (32x32 layout)
static constexpr size_t W3T_B  = 36864;    // 9*2*4*32*8  (32x32 layout)
static constexpr size_t W4T_B  = 9216;     // 9*1*4*16*8  (16x16 layout)
static constexpr size_t FW1T_B = 6422528;  // 256*12544 f16
static constexpr size_t WEIGHTS_B = W1T_B + W2T_B + W3T_B + W4T_B + FW1T_B; // 7,869,440

static constexpr size_t PB_X0 = 979200;    // 17 chunks * 900 * 32 f16
static constexpr size_t PB_X1 = 230400;    // 4 chunks
static constexpr size_t PB_X2 = 115200;    // 2 chunks
static constexpr size_t PB_X3 = 57600;     // 1 chunk
static constexpr size_t PB_X4 = 25088;     // 28*28*16 flat (fc1 k-order)
static constexpr size_t PB_X5 = 512;       // 256 f16
static constexpr size_t PER_BATCH = PB_X0 + PB_X1 + PB_X2 + PB_X3 + PB_X4 + PB_X5; // 1,408,000

// ---------------- merged weight prep (one dispatch) ----------------
// 16x16 layout (conv4): [tap][cb][hi][co][j8], ci = cb*32 + hi*8 + j
static __device__ __forceinline__ void wxf(const float* __restrict__ w, f16* __restrict__ wt,
                                           int i, int CINr, int NCB, int COUT) {
    int co = i % COUT;
    int r  = i / COUT;
    int hi = r & 3; r >>= 2;
    int cb = r % NCB;
    int tap = r / NCB;
    f16x8 v;
    #pragma unroll
    for (int j = 0; j < 8; ++j) {
        int ci = cb * 32 + hi * 8 + j;
        float x = (ci < CINr) ? w[((size_t)co * CINr + ci) * 9 + tap] : 0.f;
        v[j] = (f16)x;
    }
    *reinterpret_cast<f16x8*>(wt + (size_t)i * 8) = v;
}

// 32x32x16 layout (conv1-3): [tap][cb][kh(2)][g(2)][co][j8],
// ci = cb*32 + kh*16 + g*8 + j  (g = lane>>5 k-subgroup; pairing positional)
static __device__ __forceinline__ void wxf32g(const float* __restrict__ w,
                                              f16* __restrict__ wt, int i,
                                              int CINr, int NCB, int COUT) {
    int co = i % COUT;
    int r  = i / COUT;
    int g  = r & 1; r >>= 1;
    int kh = r & 1; r >>= 1;
    int cb = r % NCB;
    int tap = r / NCB;
    f16x8 v;
    #pragma unroll
    for (int j = 0; j < 8; ++j) {
        int ci = cb * 32 + kh * 16 + g * 8 + j;
        float x = (ci < CINr) ? w[((size_t)co * CINr + ci) * 9 + tap] : 0.f;
        v[j] = (f16)x;
    }
    *reinterpret_cast<f16x8*>(wt + (size_t)i * 8) = v;
}

static constexpr int S1 = 9 * 17 * 4 * 128;   // 78336 vec8 items
static constexpr int S2 = 9 * 4  * 4 * 64;    // 9216
static constexpr int S3 = 9 * 2  * 4 * 32;    // 2304
static constexpr int S4 = 9 * 1  * 4 * 16;    // 576
static constexpr int SW = S1 + S2 + S3 + S4;  // 90432
static constexpr int SFW = 256 * 12544;       // 3211264 scalar f16
static constexpr int PREP_TOT = SW + SFW;

__global__ void prep_all(const float* __restrict__ w1, const float* __restrict__ w2,
                         const float* __restrict__ w3, const float* __restrict__ w4,
                         const float* __restrict__ fw1,
                         f16* __restrict__ W1t, f16* __restrict__ W2t,
                         f16* __restrict__ W3t, f16* __restrict__ W4t,
                         f16* __restrict__ FW1t) {
    int t = blockIdx.x * 256 + threadIdx.x;
    if (t >= PREP_TOT) return;
    if (t < S1) { wxf32g(w1, W1t, t, 516, 17, 128); return; }
    t -= S1;
    if (t < S2) { wxf32g(w2, W2t, t, 128, 4, 64); return; }
    t -= S2;
    if (t < S3) { wxf32g(w3, W3t, t, 64, 2, 32); return; }
    t -= S3;
    if (t < S4) { wxf(w4, W4t, t, 32, 1, 16); return; }
    t -= S4;
    // fw1t[o][y*448 + x*16 + c] = fw1[o][c*784 + y*28 + x]  (k-order matches X4 flat)
    int o = t / 12544, idx = t % 12544;
    int y = idx / 448, rem = idx % 448;
    int x = rem / 16, c = rem & 15;
    FW1t[t] = (f16)fw1[(size_t)o * 12544 + c * 784 + y * 28 + x];
}

// ---------------- fused X0/ring builder (chunk-blocked): one block per batch ----------------
static __device__ __forceinline__ void ring_yx(int bi, int& y, int& x) {
    // 116 border pixels of a 30x30 tile
    if (bi < 30)      { y = 0;        x = bi; }
    else if (bi < 60) { y = 29;       x = bi - 30; }
    else if (bi < 88) { y = bi - 59;  x = 0; }      // 1..28
    else              { y = bi - 87;  x = 29; }     // 1..28
}

__global__ __launch_bounds__(512) void build_x0(
        const float* __restrict__ img, const float* __restrict__ feat,
        const float* __restrict__ centers,
        f16* __restrict__ X0, f16* __restrict__ X1,
        f16* __restrict__ X2, f16* __restrict__ X3, int b0) {
    const int bl = blockIdx.x;            // chunk-local batch
    const int b  = b0 + bl;               // global batch
    const int tid = threadIdx.x;
    f16* x0b = X0 + (size_t)bl * (17 * 900 * 32);

    // (a) X0 border ring, all 544 ch  (chunk cb=c>>5, lane c&31)
    for (int i = tid; i < 116 * 544; i += 512) {
        int c = i % 544, bi = i / 544;
        int y, x; ring_yx(bi, y, x);
        x0b[((size_t)(c >> 5) * 900 + y * 30 + x) * 32 + (c & 31)] = (f16)0.f;
    }
    // (b) cmap plane interior zero (ch 515 -> chunk 16, lane 3)
    for (int i = tid; i < 784; i += 512) {
        int y = i / 28, x = i % 28;
        x0b[((size_t)16 * 900 + (y + 1) * 30 + x + 1) * 32 + 3] = (f16)0.f;
    }
    // (c) image fill (ch 0..2 -> chunk 0)
    for (int i = tid; i < 3 * 784; i += 512) {
        int c = i / 784, p = i % 784;
        int y = p / 28, x = p % 28;
        x0b[((size_t)(y + 1) * 30 + x + 1) * 32 + c] =
            (f16)img[((size_t)b * 3 + c) * 784 + p];
    }
    // (d) bilinear 7x7 -> 28x28; tid = feat channel, maps to ch tid+3
    {
        const int c  = tid + 3;
        const int cb = c >> 5, c32 = c & 31;
        const float* fb = feat + ((size_t)b * 512 + tid) * 49;
        float r0[7], r1[7];
        int cur = -100;
        for (int y = 0; y < 28; ++y) {
            float sy = (y + 0.5f) * 0.25f - 0.5f;
            float fy = floorf(sy);
            int iy0 = (int)fy;
            float wy1 = sy - fy, wy0 = 1.f - wy1;
            if (iy0 != cur) {
                cur = iy0;
                int i0 = iy0 < 0 ? 0 : iy0;
                int i1 = (iy0 + 1 > 6) ? 6 : iy0 + 1;
                #pragma unroll
                for (int j = 0; j < 7; ++j) { r0[j] = fb[i0 * 7 + j]; r1[j] = fb[i1 * 7 + j]; }
            }
            f16* orow = x0b + ((size_t)cb * 900 + (y + 1) * 30 + 1) * 32 + c32;
            #pragma unroll 28
            for (int x = 0; x < 28; ++x) {
                float sx = (x + 0.5f) * 0.25f - 0.5f;
                float fx = floorf(sx);
                int ix0 = (int)fx;
                float wx1 = sx - fx, wx0 = 1.f - wx1;
                int j0 = ix0 < 0 ? 0 : ix0;
                int j1 = (ix0 + 1 > 6) ? 6 : ix0 + 1;
                float v = wy0 * (wx0 * r0[j0] + wx1 * r0[j1]) +
                          wy1 * (wx0 * r1[j0] + wx1 * r1[j1]);
                orow[(size_t)x * 32] = (f16)v;
            }
        }
    }
    // (e) X1/X2/X3 border rings (chunk-blocked)
    {
        f16* x1b = X1 + (size_t)bl * (4 * 900 * 32);
        for (int i = tid; i < 116 * 128; i += 512) {
            int c = i % 128, bi = i / 128;
            int y, x; ring_yx(bi, y, x);
            x1b[((size_t)(c >> 5) * 900 + y * 30 + x) * 32 + (c & 31)] = (f16)0.f;
        }
        f16* x2b = X2 + (size_t)bl * (2 * 900 * 32);
        for (int i = tid; i < 116 * 64; i += 512) {
            int c = i % 64, bi = i / 64;
            int y, x; ring_yx(bi, y, x);
            x2b[((size_t)(c >> 5) * 900 + y * 30 + x) * 32 + (c & 31)] = (f16)0.f;
        }
        f16* x3b = X3 + (size_t)bl * (900 * 32);
        for (int i = tid; i < 116 * 32; i += 512) {
            int c = i % 32, bi = i / 32;
            int y, x; ring_yx(bi, y, x);
            x3b[((size_t)y * 30 + x) * 32 + c] = (f16)0.f;
        }
    }
    __syncthreads();
    // (f) sequential scatter, last-write-wins (matches np order); ch 515 -> chunk16 lane3
    if (tid == 0) {
        const float* cb = centers + (size_t)b * 400;
        for (int n = 0; n < 100; ++n) {
            float cx = cb[n * 4 + 0], cy = cb[n * 4 + 1], conf = cb[n * 4 + 3];
            int xp = (int)(cx * 28.f);
            int yp = (int)(cy * 28.f);
            if (xp >= 0 && xp < 28 && yp >= 0 && yp < 28)
                x0b[((size_t)16 * 900 + (yp + 1) * 30 + xp + 1) * 32 + 3] = (f16)conf;
        }
    }
}

// ---------------- conv1-3: 32x32x16 MFMA template (r27 champion) ----------------
// 8-row blocks = 224 px = 7 m-tiles of 32 -> 7 waves (448 thr), each wave
// owns 1 m-tile x NCO co-tiles (acc NCO x f32x16). 2x FLOP per operand byte
// vs 16x16x32. B panel in LDS, staged per cb via async global_load_lds
// (73.7KB conv1 -> 2 blocks/CU). Measured optimum: three double-buffer
// variants (reg r16, full-DMA r28, half-DMA r29) all regressed vs this.
// A/B lane maps: row/col = lane&31, g = lane>>5; C/D map m74/m101.
template<int CIN, int COUT>
__global__ __launch_bounds__(448) void conv32(const f16* __restrict__ Xin,
                                              const f16* __restrict__ Wt,
                                              const float* __restrict__ bias,
                                              f16* __restrict__ Xout) {
    constexpr int NCB  = CIN / 32;
    constexpr int NCO  = COUT / 32;         // co-tiles per wave
    constexpr int NV_B = 9 * 4 * COUT;      // vec8 per cb panel
    constexpr int PT   = (NV_B + 447) / 448;
    __shared__ f16 Bs[NV_B * 8];

    const int rg = blockIdx.x;          // rows rg*8 .. (rg==3: only 4 rows)
    const int b  = blockIdx.y;
    const int tid = threadIdx.x;
    const int w  = tid >> 6;            // wave = m-tile 0..6
    const int lane = tid & 63;
    const int lr = lane & 31;           // A row / B col within 32-tile
    const int g  = lane >> 5;           // k-subgroup
    const int PV = ((rg < 3) ? 8 : 4) * 28;   // valid px in block
    const int p  = w * 32 + lr;
    const int pc = (p < PV) ? p : 0;    // clamped (garbage rows never stored)
    const int yl = pc / 28, xx = pc - yl * 28;
    const int pixoff = (rg * 8 + yl) * 30 + xx;   // padded-coord pixel offset

    f32x16 acc[NCO];
    #pragma unroll
    for (int n = 0; n < NCO; ++n)
        #pragma unroll
        for (int r = 0; r < 16; ++r) acc[n][r] = 0.f;

    const size_t bbase = (size_t)b * NCB * 900;

    for (int cb = 0; cb < NCB; ++cb) {
        // stage B panel async (wave-uniform LDS base + lane*16)
        #pragma unroll
        for (int pi = 0; pi < PT; ++pi) {
            const int v = tid + pi * 448;
            if (v < NV_B) {
                const int tap = v / (4 * COUT);
                const int w2  = v - tap * (4 * COUT);
                const f16* gsrc = Wt + ((size_t)(tap * NCB + cb) * (4 * COUT) + w2) * 8;
                f16* ldst = Bs + (size_t)(pi * 448 + (tid & ~63)) * 8;
                __builtin_amdgcn_global_load_lds(
                    (const __attribute__((address_space(1))) void*)gsrc,
                    (__attribute__((address_space(3))) void*)ldst, 16, 0, 0);
            }
        }
        __syncthreads();

        #pragma unroll
        for (int tap = 0; tap < 9; ++tap) {
            const int dy = tap / 3, dx = tap - dy * 3;
            const size_t abase = (bbase + (size_t)cb * 900 + pixoff + dy * 30 + dx) * 32 + g * 8;
            const f16x8 a0 = ld8(Xin + abase);        // kh=0
            const f16x8 a1 = ld8(Xin + abase + 16);   // kh=1
            #pragma unroll
            for (int n = 0; n < NCO; ++n) {
                const f16x8 b0 = *reinterpret_cast<const f16x8*>(
                    Bs + ((size_t)((tap * 4 + 0 * 2 + g) * COUT) + n * 32 + lr) * 8);
                const f16x8 b1 = *reinterpret_cast<const f16x8*>(
                    Bs + ((size_t)((tap * 4 + 1 * 2 + g) * COUT) + n * 32 + lr) * 8);
                acc[n] = __builtin_amdgcn_mfma_f32_32x32x16_f16(a0, b0, acc[n], 0, 0, 0);
                acc[n] = __builtin_amdgcn_mfma_f32_32x32x16_f16(a1, b1, acc[n], 0, 0, 0);
            }
        }
        __syncthreads();
    }

    // epilogue: col = n*32+lr, row = (r&3)+8*(r>>2)+4*g (m74/m101 layout)
    #pragma unroll
    for (int n = 0; n < NCO; ++n) {
        const int co = n * 32 + lr;
        const float bv = bias[co];
        #pragma unroll
        for (int r = 0; r < 16; ++r) {
            const int row = (r & 3) + 8 * (r >> 2) + 4 * g;
            const int pp = w * 32 + row;
            if (pp < PV) {
                const int yy = pp / 28, xo = pp - yy * 28;
                const size_t off = (((size_t)b * NCO + (co >> 5)) * 900 +
                                    (rg * 8 + yy + 1) * 30 + (xo + 1)) * 32 + (co & 31);
                Xout[off] = (f16)fmaxf(acc[n][r] + bv, 0.f);
            }
        }
    }
}

// ---------------- conv4: 16x16x32 template ----------------
template<int CIN, int COUT, int GM, int GN, int WNT, int MW, bool PADOUT>
__global__ __launch_bounds__(512) void conv3x3(const f16* __restrict__ Xin,
                                               const f16* __restrict__ Wt,
                                               const float* __restrict__ bias,
                                               f16* __restrict__ Xout) {
    constexpr int NCB  = CIN / 32;
    constexpr int NCBO = COUT / 32;
    constexpr int NV_B = 9 * 4 * COUT;
    constexpr int PT   = (NV_B + 511) / 512;
    __shared__ f16 Bs[NV_B * 8];

    const int rg = blockIdx.x;
    const int b  = blockIdx.y;
    const int tid = threadIdx.x;
    const int wave = tid >> 6;
    const int lane = tid & 63;
    const int lm = lane & 15, hi = lane >> 4;
    const int wm = wave % GM, wn = wave / GM;
    const int MT = (rg < 3) ? 14 : 7;

    f32x4 acc[MW][WNT];
    #pragma unroll
    for (int k = 0; k < MW; ++k)
        #pragma unroll
        for (int n = 0; n < WNT; ++n)
            acc[k][n] = (f32x4){0.f, 0.f, 0.f, 0.f};

    const size_t bbase = (size_t)b * NCB * 900;
    int inoff[MW];
    #pragma unroll
    for (int k = 0; k < MW; ++k) {
        const int m = wm + k * GM;
        const int p = m * 16 + lm;
        const int yl = p / 28, x = p - yl * 28;
        inoff[k] = (m < MT) ? ((rg * 8 + yl) * 30 + x) : 0;
    }

    for (int cb = 0; cb < NCB; ++cb) {
        #pragma unroll
        for (int pi = 0; pi < PT; ++pi) {
            const int v = tid + pi * 512;
            if (v < NV_B) {
                const int tap = v / (4 * COUT);
                const int w   = v - tap * (4 * COUT);
                const f16* gsrc = Wt + ((size_t)(tap * NCB + cb) * (4 * COUT) + w) * 8;
                f16* ldst = Bs + (size_t)(pi * 512 + (tid & ~63)) * 8;
                __builtin_amdgcn_global_load_lds(
                    (const __attribute__((address_space(1))) void*)gsrc,
                    (__attribute__((address_space(3))) void*)ldst, 16, 0, 0);
            }
        }
        __syncthreads();

        #pragma unroll
        for (int tap = 0; tap < 9; ++tap) {
            f16x8 bf[WNT];
            #pragma unroll
            for (int n = 0; n < WNT; ++n)
                bf[n] = *reinterpret_cast<const f16x8*>(
                    Bs + ((size_t)(tap * 4 + hi) * COUT + (wn * WNT + n) * 16 + lm) * 8);
            const int dy = tap / 3, dx = tap - dy * 3;
            const size_t dOff = (bbase + (size_t)cb * 900 + dy * 30 + dx) * 32 + hi * 8;
            #pragma unroll
            for (int k = 0; k < MW; ++k) {
                if (wm + k * GM < MT) {
                    const f16x8 af = ld8(Xin + dOff + (size_t)inoff[k] * 32);
                    #pragma unroll
                    for (int n = 0; n < WNT; ++n)
                        acc[k][n] = __builtin_amdgcn_mfma_f32_16x16x32_f16(af, bf[n], acc[k][n], 0, 0, 0);
                }
            }
        }
        __syncthreads();
    }

    #pragma unroll
    for (int k = 0; k < MW; ++k) {
        const int m = wm + k * GM;
        if (m < MT) {
            #pragma unroll
            for (int n = 0; n < WNT; ++n) {
                const int co = (wn * WNT + n) * 16 + lm;
                const float bv = bias[co];
                #pragma unroll
                for (int r = 0; r < 4; ++r) {
                    const int p = m * 16 + hi * 4 + r;
                    const int yl = p / 28, x = p - yl * 28;
                    const float v = fmaxf(acc[k][n][r] + bv, 0.f);
                    size_t off;
                    if (PADOUT)
                        off = (((size_t)b * NCBO + (co >> 5)) * 900 +
                               (rg * 8 + yl + 1) * 30 + (x + 1)) * 32 + (co & 31);
                    else
                        off = ((size_t)b * 784 + (rg * 8 + yl) * 28 + x) * COUT + co;
                    Xout[off] = (f16)v;
                }
            }
        }
    }
}

// ---------------- FC layers ----------------
__global__ __launch_bounds__(256) void fc1k(const f16* __restrict__ X4,
                                            const f16* __restrict__ FW1t,
                                            const float* __restrict__ fb1,
                                            f16* __restrict__ X5, int CH) {
    const int bm = blockIdx.x;
    const int nt = blockIdx.y * 4 + (threadIdx.x >> 6);
    const int lane = threadIdx.x & 63;
    const int lm = lane & 15, hi = lane >> 4;
    f32x4 acc = (f32x4){0.f, 0.f, 0.f, 0.f};
    const int row0 = bm * 16 + lm;
    const int rowA = (row0 < CH) ? row0 : 0;
    const f16* arow = X4 + (size_t)rowA * 12544;
    const int o = nt * 16 + lm;
    const f16* brow = FW1t + (size_t)o * 12544;
    for (int kk = 0; kk < 12544; kk += 32) {
        const f16x8 af = ld8(arow + kk + hi * 8);
        const f16x8 bf = ld8(brow + kk + hi * 8);
        acc = __builtin_amdgcn_mfma_f32_16x16x32_f16(af, bf, acc, 0, 0, 0);
    }
    const float bv = fb1[o];
    #pragma unroll
    for (int r = 0; r < 4; ++r) {
        const int row = bm * 16 + hi * 4 + r;
        if (row < CH)
            X5[(size_t)row * 256 + o] = (f16)fmaxf(acc[r] + bv, 0.f);
    }
}

__global__ void fc2k(const f16* __restrict__ X5, const float* __restrict__ fw2,
                     const float* __restrict__ fb2, float* __restrict__ out, int CH) {
    int t = blockIdx.x * 256 + threadIdx.x;
    if (t < CH * 24) {
        int b = t / 24, o = t % 24;
        float s = fb2[o];
        const f16* xr = X5 + (size_t)b * 256;
        const float* wr = fw2 + (size_t)o * 256;
        for (int k = 0; k < 256; ++k) s += (float)xr[k] * wr[k];
        if (o == 2 || o == 3) s = 1.f / (1.f + expf(-s));
        out[t] = s;
    }
}

// ---------------- launch ----------------
extern "C" void kernel_launch(void* const* d_in, const int* in_sizes, int n_in,
                              void* d_out, int out_size, void* d_ws, size_t ws_size,
                              hipStream_t stream) {
    const float* image    = (const float*)d_in[0];
    const float* features = (const float*)d_in[1];
    const float* centers  = (const float*)d_in[2];
    const float* w1  = (const float*)d_in[3];
    const float* b1  = (const float*)d_in[4];
    const float* w2  = (const float*)d_in[5];
    const float* b2  = (const float*)d_in[6];
    const float* w3  = (const float*)d_in[7];
    const float* b3  = (const float*)d_in[8];
    const float* w4  = (const float*)d_in[9];
    const float* b4  = (const float*)d_in[10];
    const float* fw1 = (const float*)d_in[11];
    const float* fb1 = (const float*)d_in[12];
    const float* fw2 = (const float*)d_in[13];
    const float* fb2 = (const float*)d_in[14];

    // pick largest chunk (batches per pass) that fits ws_size; CH divides 256
    int CH = 8;
    for (int c = 256; c >= 8; c >>= 1) {
        if (WEIGHTS_B + (size_t)c * PER_BATCH <= ws_size) { CH = c; break; }
    }

    char* ws = (char*)d_ws;
    f16* W1t  = (f16*)(ws);
    f16* W2t  = (f16*)(ws + W1T_B);
    f16* W3t  = (f16*)(ws + W1T_B + W2T_B);
    f16* W4t  = (f16*)(ws + W1T_B + W2T_B + W3T_B);
    f16* FW1t = (f16*)(ws + W1T_B + W2T_B + W3T_B + W4T_B);
    char* act = ws + WEIGHTS_B;
    f16* X0 = (f16*)(act);
    f16* X1 = (f16*)(act + (size_t)CH * PB_X0);
    f16* X2 = (f16*)(act + (size_t)CH * (PB_X0 + PB_X1));
    f16* X3 = (f16*)(act + (size_t)CH * (PB_X0 + PB_X1 + PB_X2));
    f16* X4 = (f16*)(act + (size_t)CH * (PB_X0 + PB_X1 + PB_X2 + PB_X3));
    f16* X5 = (f16*)(act + (size_t)CH * (PB_X0 + PB_X1 + PB_X2 + PB_X3 + PB_X4));

    prep_all<<<(PREP_TOT + 255) / 256, 256, 0, stream>>>(w1, w2, w3, w4, fw1,
                                                         W1t, W2t, W3t, W4t, FW1t);

    for (int b0 = 0; b0 < 256; b0 += CH) {
        build_x0<<<CH, 512, 0, stream>>>(image, features, centers,
                                         X0, X1, X2, X3, b0);

        dim3 cgrid(4, CH);
        conv32<544, 128><<<cgrid, 448, 0, stream>>>(X0, W1t, b1, X1);
        conv32<128, 64 ><<<cgrid, 448, 0, stream>>>(X1, W2t, b2, X2);
        conv32<64,  32 ><<<cgrid, 448, 0, stream>>>(X2, W3t, b3, X3);
        conv3x3<32, 16, 8, 1, 1, 2, false><<<cgrid, 512, 0, stream>>>(X3, W4t, b4, X4);

        dim3 fgrid((CH + 15) / 16, 4);
        fc1k<<<fgrid, 256, 0, stream>>>(X4, FW1t, fb1, X5, CH);
        fc2k<<<(CH * 24 + 255) / 256, 256, 0, stream>>>(X5, fw2, fb2,
                                                        (float*)d_out + (size_t)b0 * 24, CH);
    }
}